// Round 9
// baseline (426.951 us; speedup 1.0000x reference)
//
#include <hip/hip_runtime.h>

// Submanifold sparse conv 3x3x3, G=128, Cin=Cout=32.
// R15: single persistent kernel (+8B memset). Evidence: non-conv = ~18us/node
// + ~70us opaque residue (prep never surfaces in top-5); conv schedule-
// invariant ~121-130us in both regimes. Merge table-init/build/convert/conv
// into ONE dispatch with a manual device-scope global barrier:
//  - grid=768=3 blocks/CU exactly (LDS 3x53248<=160K, 24 waves<=32, VGPR<=64
//    -> statically co-resident; launch_bounds(512,6) per guide rule)
//  - BOUNDED spin (2e9 iters): co-residency failure -> absmax fail, container
//    SURVIVES (R12 coop abort / R13 OOB death lessons: never hang, never OOB)
//  - barrier counters = 8B zeroed by the only memset node (workspace may be
//    poisoned; counters are the only state needing external init)
// Conv body is byte-identical to R14 (center tap via compiler loads, saddr
// asm gathers, depth-6 rolling window, counted WAITV(5), conflict-free LDS
// weight layout, zero-row), wrapped in a grid-stride tile-block loop.
// Workspace: table 8MB | wtT 64KB | featsB 32MB+64B | bar 8B (~40.07MB).

#define GRID 128
#define CIN 32
#define COUT 32
#define NOFF 27
#define NB 768          // persistent grid: 3 blocks/CU x 256 CUs

typedef __attribute__((ext_vector_type(8))) short bf16x8;
typedef __attribute__((ext_vector_type(4))) float f32x4;

__device__ inline unsigned short f2bf(float x) {
    union { float f; unsigned u; } v; v.f = x;
    unsigned r = v.u + 0x7fff + ((v.u >> 16) & 1);   // RTNE
    return (unsigned short)(r >> 16);
}

// Bounded-spin one-shot global barrier (device scope). Safe by construction:
// worst case is timeout (wrong output, surviving container), never deadlock.
__device__ __forceinline__ void gbar(int* cnt) {
    __syncthreads();
    if (threadIdx.x == 0) {
        __threadfence();                       // release prior writes (device)
        atomicAdd(cnt, 1);                     // device-scope by default (m20)
        volatile int* vc = (volatile int*)cnt;
        long t = 0;
        while (*vc < NB && t < 2000000000L) ++t;
        __threadfence();                       // acquire side
    }
    __syncthreads();
}

#define SBAR() __builtin_amdgcn_sched_barrier(0)
#define WAITV(n) asm volatile("s_waitcnt vmcnt(" #n ")" ::: "memory")
// saddr form: 32-bit byte voffset (VGPR) + 64-bit base (SGPR pair)
#define GLOAD(dst, ss) \
    asm volatile("global_load_dwordx4 %0, %1, %2" \
                 : "=v"(dst) : "v"(voff[ss]), "s"(featsB));

#define STEPL(areg, kk) { \
    bf16x8 b0_ = *(const bf16x8*)(wb + (kk) * 1024); \
    bf16x8 b1_ = *(const bf16x8*)(wb + (kk) * 1024 + 512); \
    acc0 = __builtin_amdgcn_mfma_f32_16x16x32_bf16(areg, b0_, acc0, 0, 0, 0); \
    acc1 = __builtin_amdgcn_mfma_f32_16x16x32_bf16(areg, b1_, acc1, 0, 0, 0); }

__global__ __launch_bounds__(512, 6)
void fused_kernel(const float* __restrict__ feats,
                  const int* __restrict__ pos,
                  const float* __restrict__ wt,
                  int* __restrict__ table,
                  unsigned short* __restrict__ wtT,
                  unsigned short* __restrict__ featsB,
                  float* __restrict__ out,
                  int* __restrict__ bar,
                  int N, int elems4, int numTileBlocks) {
    __shared__ __align__(16) unsigned short ldsw[26 * 1024]; // 53248 B -> 3 blk/CU

    int tid = threadIdx.x;
    int gtid = (int)blockIdx.x * 512 + tid;
    const int gsz = NB * 512;

    // ---- Phase 0: table init (replaces the 8MB memset node) ----
    for (int j = gtid; j < GRID * GRID * GRID; j += gsz) table[j] = -1;
    gbar(&bar[0]);

    // ---- Phase 1: table build + fp32->bf16 convert + weight transpose ----
    for (int i = gtid; i < N; i += gsz) {
        int x = pos[3 * i], y = pos[3 * i + 1], z = pos[3 * i + 2];
        atomicMax(&table[(x * GRID + y) * GRID + z], i);   // max-id-wins
    }
    unsigned* fB = (unsigned*)featsB;
    for (int i = gtid; i < elems4; i += gsz) {             // 4 fp32 -> 4 bf16
        float4 v = ((const float4*)feats)[i];
        uint2 o;
        o.x = (unsigned)f2bf(v.x) | ((unsigned)f2bf(v.y) << 16);
        o.y = (unsigned)f2bf(v.z) | ((unsigned)f2bf(v.w) << 16);
        ((uint2*)fB)[i + 8] = o;             // +8 uint2 = row shift (+1 row)
    }
    if (gtid < 8) ((uint2*)fB)[gtid] = (uint2){0u, 0u};    // zero row 0
    for (int i = gtid; i < NOFF * CIN * COUT; i += gsz) {
        int k = i >> 10, r = i & 1023, ci = r >> 5, co = r & 31;
        int d = k * 1024 + (co >= 16 ? 512 : 0) + (ci >> 3) * 128 + (co & 15) * 8 + (ci & 7);
        wtT[d] = f2bf(wt[i]);
    }
    gbar(&bar[1]);

    // ---- Phase 2: conv (R14 body in a grid-stride tile-block loop) ----
    int wave = tid >> 6, lane = tid & 63;
    int m = lane & 15, quad = lane >> 4;
    int qb = quad * 16;

    // Stage 26 W^T slices (k != 13) into LDS once; remap source index.
    {
        const uint4* src = (const uint4*)wtT;       // [27][128] uint4
        uint4* dst = (uint4*)ldsw;                  // [26][128] uint4
        for (int e = tid; e < 26 * 128; e += 512) {
            int ks = e >> 7; ks += (ks >= 13);
            dst[e] = src[ks * 128 + (e & 127)];
        }
    }
    __syncthreads();
    // conflict-free: 16-lane phase (quad fixed) reads 16 contiguous 16B slots
    const unsigned short* wb = ldsw + quad * 128 + m * 8;

    for (int tb = (int)blockIdx.x; tb < numTileBlocks; tb += NB) {
        int tile = tb * 8 + wave;
        int base = tile * 16;
        int g = base + m;
        bool gv = g < N;

        int x = 0, y = 0, z = 0;
        if (gv) { x = pos[3 * g]; y = pos[3 * g + 1]; z = pos[3 * g + 2]; }
        int key = (x * GRID + y) * GRID + z;
        bool v0[3] = {gv && x > 0, gv, gv && x < GRID - 1};
        bool v1[3] = {gv && y > 0, gv, gv && y < GRID - 1};
        bool v2[3] = {gv && z > 0, gv, gv && z < GRID - 1};

        // Phase A: 26 ring-tap lookups -> byte voffsets (skip k=13).
        int voff[26];
#pragma unroll
        for (int s = 0; s < 26; ++s) {
            const int k = s + (s >= 13);
            const int dx = k / 9, dy = (k / 3) % 3, dz = k % 3;
            bool ok = v0[dx] && v1[dy] && v2[dz];
            int hk = key + (dx - 1) * GRID * GRID + (dy - 1) * GRID + (dz - 1);
            hk = ok ? hk : 0;
            int id = table[hk];
            voff[s] = ((ok && id >= 0) ? (id + 1) * 64 : 0) + qb;
        }

        f32x4 acc0 = {0.f, 0.f, 0.f, 0.f};
        f32x4 acc1 = {0.f, 0.f, 0.f, 0.f};

        // Center tap (k=13): compiler loads + 2 MFMA before the asm region
        // (unaware compiler waitcnts only over-wait -> count-safe).
        {
            int idc = table[key];
            int vc = ((gv && idc >= 0) ? (idc + 1) * 64 : 0) + qb;
            bf16x8 ac = *(const bf16x8*)((const char*)featsB + vc);
            const unsigned short* wc = wtT + 13 * 1024 + quad * 128 + m * 8;
            bf16x8 wc0 = *(const bf16x8*)(wc);
            bf16x8 wc1 = *(const bf16x8*)(wc + 512);
            acc0 = __builtin_amdgcn_mfma_f32_16x16x32_bf16(ac, wc0, acc0, 0, 0, 0);
            acc1 = __builtin_amdgcn_mfma_f32_16x16x32_bf16(ac, wc1, acc1, 0, 0, 0);
        }
        SBAR();   // pin center compute above the asm pipeline

        bf16x8 c0, c1, c2, c3, c4, c5;
        GLOAD(c0, 0) GLOAD(c1, 1) GLOAD(c2, 2)
        GLOAD(c3, 3) GLOAD(c4, 4) GLOAD(c5, 5)

        // Steady state: consume buf s%6, reload gather s+6; counted vmcnt.
        WAITV(5); SBAR(); STEPL(c0, 0)  GLOAD(c0, 6)
        WAITV(5); SBAR(); STEPL(c1, 1)  GLOAD(c1, 7)
        WAITV(5); SBAR(); STEPL(c2, 2)  GLOAD(c2, 8)
        WAITV(5); SBAR(); STEPL(c3, 3)  GLOAD(c3, 9)
        WAITV(5); SBAR(); STEPL(c4, 4)  GLOAD(c4, 10)
        WAITV(5); SBAR(); STEPL(c5, 5)  GLOAD(c5, 11)
        WAITV(5); SBAR(); STEPL(c0, 6)  GLOAD(c0, 12)
        WAITV(5); SBAR(); STEPL(c1, 7)  GLOAD(c1, 13)
        WAITV(5); SBAR(); STEPL(c2, 8)  GLOAD(c2, 14)
        WAITV(5); SBAR(); STEPL(c3, 9)  GLOAD(c3, 15)
        WAITV(5); SBAR(); STEPL(c4, 10) GLOAD(c4, 16)
        WAITV(5); SBAR(); STEPL(c5, 11) GLOAD(c5, 17)
        WAITV(5); SBAR(); STEPL(c0, 12) GLOAD(c0, 18)
        WAITV(5); SBAR(); STEPL(c1, 13) GLOAD(c1, 19)
        WAITV(5); SBAR(); STEPL(c2, 14) GLOAD(c2, 20)
        WAITV(5); SBAR(); STEPL(c3, 15) GLOAD(c3, 21)
        WAITV(5); SBAR(); STEPL(c4, 16) GLOAD(c4, 22)
        WAITV(5); SBAR(); STEPL(c5, 17) GLOAD(c5, 23)
        WAITV(5); SBAR(); STEPL(c0, 18) GLOAD(c0, 24)
        WAITV(5); SBAR(); STEPL(c1, 19) GLOAD(c1, 25)
        WAITV(5); SBAR(); STEPL(c2, 20)
        WAITV(4); SBAR(); STEPL(c3, 21)
        WAITV(3); SBAR(); STEPL(c4, 22)
        WAITV(2); SBAR(); STEPL(c5, 23)
        WAITV(1); SBAR(); STEPL(c0, 24)
        WAITV(0); SBAR(); STEPL(c1, 25)

        // D layout: col = lane&15 = co, row = quad*4 + i. Coalesced writes.
#pragma unroll
        for (int i = 0; i < 4; ++i) {
            int p = base + quad * 4 + i;
            if (p < N) {
                out[(size_t)p * COUT + m]      = acc0[i];
                out[(size_t)p * COUT + m + 16] = acc1[i];
            }
        }
    }
}

extern "C" void kernel_launch(void* const* d_in, const int* in_sizes, int n_in,
                              void* d_out, int out_size, void* d_ws, size_t ws_size,
                              hipStream_t stream) {
    const float* feats = (const float*)d_in[0];   // [N, 32]
    const int*   pos   = (const int*)d_in[1];     // [N, 3]
    const float* wt    = (const float*)d_in[2];   // [27, 32, 32]
    float* out = (float*)d_out;                   // [N, 32]
    int N = in_sizes[0] / CIN;

    char* ws = (char*)d_ws;
    size_t off = 0;
    int* table = (int*)(ws + off);            off += (size_t)GRID * GRID * GRID * 4; // 8 MB
    unsigned short* wtT = (unsigned short*)(ws + off); off += 65536;                 // 64 KB
    unsigned short* featsB = (unsigned short*)(ws + off);
    off += (size_t)(500224 + 1) * CIN * 2 + 64;                                      // 32 MB + pad
    int* bar = (int*)(ws + off);                                                     // 8 B

    hipMemsetAsync(bar, 0, 2 * sizeof(int), stream);      // the only init node

    int elems4 = N * CIN / 4;
    int numTileBlocks = ((N + 15) / 16 + 7) / 8;
    fused_kernel<<<NB, 512, 0, stream>>>(feats, pos, wt, table, wtT, featsB,
                                         out, bar, N, elems4, numTileBlocks);
}

// Round 10
// 263.333 us; speedup vs baseline: 1.6213x; 1.6213x over previous
//
#include <hip/hip_runtime.h>

// Submanifold sparse conv 3x3x3, G=128, Cin=Cout=32.
// R16: scratch-free two-stream asm pipeline. Root cause finally isolated:
// VGPR=40-52 across ALL pipeline attempts => rows[]/voff[] locals were
// SROA'd to SCRATCH; each step's compiler scratch-reload emits its own
// s_waitcnt vmcnt(0) (compiler can't see asm loads) -> drains the gather
// pipeline every step -> serial 121-130us regardless of schedule. R15's
// persistent loop amplified it (348us); persistent reverted.
// Fix: ZERO local arrays. Validity = one 27-bit mask reg. Table lookups are
// an asm load stream (t0..t6 ring, 6 steps ahead of gathers); feature
// gathers are a second asm stream (g0..g6 ring, 6 ahead of MFMA). One
// hand-counted WAITV per step covers both (FIFO simulated; steady N=10).
// T0..T5 hide under LDS staging (WAITV(0)+barrier), center tap (k=13) done
// with compiler loads BEFORE any asm issue. Structure = R14's proven 3
// nodes / 40.07MB workspace.
// Falsifier: VGPR must jump to ~60-85. If still <=48, scalarization failed.

#define GRID 128
#define CIN 32
#define COUT 32
#define NOFF 27

typedef __attribute__((ext_vector_type(8))) short bf16x8;
typedef __attribute__((ext_vector_type(4))) float f32x4;

__device__ inline unsigned short f2bf(float x) {
    union { float f; unsigned u; } v; v.f = x;
    unsigned r = v.u + 0x7fff + ((v.u >> 16) & 1);   // RTNE
    return (unsigned short)(r >> 16);
}

// K1: fused prep (identical to R14's proven kernel):
//  - feats fp32 -> bf16 rows shifted +1 (row 0 = zeros)
//  - table atomicMax (numpy max-index-wins), table pre-memset to -1
//  - weight transpose [27][ci][co] -> [k][half(co>=16)][quad(ci>>3)][m][e]
__global__ void prep_kernel(const float* __restrict__ feats,
                            const int* __restrict__ pos,
                            const float* __restrict__ wt,
                            int* __restrict__ table,
                            unsigned short* __restrict__ wtT,
                            unsigned* __restrict__ featsB,
                            int N, int elems4) {
    int i = blockIdx.x * 256 + threadIdx.x;
    if (i < elems4) {
        float4 v = ((const float4*)feats)[i];
        uint2 o;
        o.x = (unsigned)f2bf(v.x) | ((unsigned)f2bf(v.y) << 16);
        o.y = (unsigned)f2bf(v.z) | ((unsigned)f2bf(v.w) << 16);
        ((uint2*)featsB)[i + 8] = o;       // +8 uint2 = +1 row shift
    }
    if (i < 8) ((uint2*)featsB)[i] = (uint2){0u, 0u};   // zero row 0
    if (i < N) {
        int x = pos[3 * i], y = pos[3 * i + 1], z = pos[3 * i + 2];
        atomicMax(&table[(x * GRID + y) * GRID + z], i);
    }
    if (i < NOFF * CIN * COUT) {
        int k = i >> 10, r = i & 1023, ci = r >> 5, co = r & 31;
        int d = k * 1024 + (co >= 16 ? 512 : 0) + (ci >> 3) * 128 + (co & 15) * 8 + (ci & 7);
        wtT[d] = f2bf(wt[i]);
    }
}

// ---- conv: two-stream asm pipeline, all state in named scalars ----
#define SBAR() __builtin_amdgcn_sched_barrier(0)
#define WAITV(n) asm volatile("s_waitcnt vmcnt(" #n ")" ::: "memory")
#define KOF(j) ((j) + ((j) >= 13))                 // pipeline idx -> tap k
#define COF(j) (((KOF(j) / 9) - 1) * 16384 + (((KOF(j) / 3) % 3) - 1) * 128 + ((KOF(j) % 3) - 1))

// Issue table lookup for pipeline index j into t-ring slot ts.
#define TLOAD(ts, j) { \
    int ok_ = (mask >> KOF(j)) & 1; \
    int hk_ = ok_ ? (key + (COF(j))) : 0; \
    asm volatile("global_load_dword %0, %1, %2" \
                 : "=v"(t##ts) : "v"(hk_ * 4), "s"(table)); }

// Issue feature gather for pipeline index j (t-ring slot ts -> g-ring slot gs).
#define GLOAD(gs, ts, j) { \
    int ok_ = (mask >> KOF(j)) & 1; \
    int vo_ = ((ok_ && t##ts >= 0) ? ((t##ts + 1) << 6) : 0) + qb; \
    asm volatile("global_load_dwordx4 %0, %1, %2" \
                 : "=v"(g##gs) : "v"(vo_), "s"(featsB)); }

// MFMA pair for step s consuming g-ring slot gs (weights from LDS slice s).
#define MM(gs, s) { \
    bf16x8 b0_ = *(const bf16x8*)(wb + (s) * 1024); \
    bf16x8 b1_ = *(const bf16x8*)(wb + (s) * 1024 + 512); \
    acc0 = __builtin_amdgcn_mfma_f32_16x16x32_bf16(g##gs, b0_, acc0, 0, 0, 0); \
    acc1 = __builtin_amdgcn_mfma_f32_16x16x32_bf16(g##gs, b1_, acc1, 0, 0, 0); }

__global__ __launch_bounds__(512, 6)
void conv_kernel(const unsigned short* __restrict__ featsB,
                 const int* __restrict__ pos,
                 const unsigned short* __restrict__ wtT,
                 const int* __restrict__ table,
                 float* __restrict__ out, int N) {
    __shared__ __align__(16) unsigned short ldsw[26 * 1024]; // 53248 B -> 3 blk/CU

    int tid = threadIdx.x;
    int wave = tid >> 6, lane = tid & 63;
    int m = lane & 15, quad = lane >> 4;
    int qb = quad * 16;
    int tile = (int)blockIdx.x * 8 + wave;
    int base = tile * 16;
    int g = base + m;
    bool gv = g < N;

    int x = 0, y = 0, z = 0;
    if (gv) { x = pos[3 * g]; y = pos[3 * g + 1]; z = pos[3 * g + 2]; }
    int key = (x * GRID + y) * GRID + z;

    // 27-bit validity mask in ONE register (no bool arrays -> no scratch).
    int mx = (gv && x > 0 ? 1 : 0) | (gv ? 2 : 0) | (gv && x < GRID - 1 ? 4 : 0);
    int my = (gv && y > 0 ? 1 : 0) | (gv ? 2 : 0) | (gv && y < GRID - 1 ? 4 : 0);
    int mz = (gv && z > 0 ? 1 : 0) | (gv ? 2 : 0) | (gv && z < GRID - 1 ? 4 : 0);
    int mask = 0;
#pragma unroll
    for (int k = 0; k < NOFF; ++k)
        mask |= (((mx >> (k / 9)) & (my >> ((k / 3) % 3)) & (mz >> (k % 3))) & 1) << k;

    f32x4 acc0 = {0.f, 0.f, 0.f, 0.f};
    f32x4 acc1 = {0.f, 0.f, 0.f, 0.f};

    // Center tap (k=13): compiler loads fully BEFORE any asm issue, so the
    // compiler's own waitcnts see only its own loads (count-safe).
    {
        int idc = table[key];
        int vc = ((gv && idc >= 0) ? (idc + 1) * 64 : 0) + qb;
        bf16x8 ac = *(const bf16x8*)((const char*)featsB + vc);
        const unsigned short* wc = wtT + 13 * 1024 + quad * 128 + m * 8;
        bf16x8 wc0 = *(const bf16x8*)(wc);
        bf16x8 wc1 = *(const bf16x8*)(wc + 512);
        acc0 = __builtin_amdgcn_mfma_f32_16x16x32_bf16(ac, wc0, acc0, 0, 0, 0);
        acc1 = __builtin_amdgcn_mfma_f32_16x16x32_bf16(ac, wc1, acc1, 0, 0, 0);
    }
    SBAR();

    int t0, t1, t2, t3, t4, t5, t6;
    bf16x8 g0, g1, g2, g3, g4, g5, g6;

    // T-prologue: 6 table lookups in flight; they complete under LDS staging.
    TLOAD(0, 0) TLOAD(1, 1) TLOAD(2, 2) TLOAD(3, 3) TLOAD(4, 4) TLOAD(5, 5)

    // Stage 26 W^T slices (k != 13) into LDS; remap source index.
    {
        const uint4* src = (const uint4*)wtT;       // [27][128] uint4
        uint4* dst = (uint4*)ldsw;                  // [26][128] uint4
        for (int e = tid; e < 26 * 128; e += 512) {
            int ks = e >> 7; ks += (ks >= 13);
            dst[e] = src[ks * 128 + (e & 127)];
        }
    }
    WAITV(0);          // drain T0..T5 + staging loads (t-values now valid)
    __syncthreads();
    SBAR();            // nothing crosses above the drain/barrier

    // conflict-free: 16-lane phase (quad fixed) reads 16 contiguous 16B slots
    const unsigned short* wb = ldsw + quad * 128 + m * 8;

    // G-prologue: interleave G0..G5 with T6..T11 (FIFO == steady pattern).
    GLOAD(0, 0, 0)  TLOAD(6, 6)
    GLOAD(1, 1, 1)  TLOAD(0, 7)
    GLOAD(2, 2, 2)  TLOAD(1, 8)
    GLOAD(3, 3, 3)  TLOAD(2, 9)
    GLOAD(4, 4, 4)  TLOAD(3, 10)
    GLOAD(5, 5, 5)  TLOAD(4, 11)

    // Steps s=0..25. Per step: one counted wait covers T_{s+6} and G_s
    // (hand-simulated FIFO; steady N=10, tail descends). Read g[s%7],
    // t[(s+6)%7]; write G_{s+6}->g[(s+6)%7], T_{s+12}->t[(s+5)%7].
    WAITV(10); SBAR(); GLOAD(6, 6, 6)   TLOAD(5, 12)  MM(0, 0)
    WAITV(10); SBAR(); GLOAD(0, 0, 7)   TLOAD(6, 13)  MM(1, 1)
    WAITV(10); SBAR(); GLOAD(1, 1, 8)   TLOAD(0, 14)  MM(2, 2)
    WAITV(10); SBAR(); GLOAD(2, 2, 9)   TLOAD(1, 15)  MM(3, 3)
    WAITV(10); SBAR(); GLOAD(3, 3, 10)  TLOAD(2, 16)  MM(4, 4)
    WAITV(10); SBAR(); GLOAD(4, 4, 11)  TLOAD(3, 17)  MM(5, 5)
    WAITV(10); SBAR(); GLOAD(5, 5, 12)  TLOAD(4, 18)  MM(6, 6)
    WAITV(10); SBAR(); GLOAD(6, 6, 13)  TLOAD(5, 19)  MM(0, 7)
    WAITV(10); SBAR(); GLOAD(0, 0, 14)  TLOAD(6, 20)  MM(1, 8)
    WAITV(10); SBAR(); GLOAD(1, 1, 15)  TLOAD(0, 21)  MM(2, 9)
    WAITV(10); SBAR(); GLOAD(2, 2, 16)  TLOAD(1, 22)  MM(3, 10)
    WAITV(10); SBAR(); GLOAD(3, 3, 17)  TLOAD(2, 23)  MM(4, 11)
    WAITV(10); SBAR(); GLOAD(4, 4, 18)  TLOAD(3, 24)  MM(5, 12)
    WAITV(10); SBAR(); GLOAD(5, 5, 19)  TLOAD(4, 25)  MM(6, 13)
    WAITV(10); SBAR(); GLOAD(6, 6, 20)                MM(0, 14)
    WAITV(9);  SBAR(); GLOAD(0, 0, 21)                MM(1, 15)
    WAITV(8);  SBAR(); GLOAD(1, 1, 22)                MM(2, 16)
    WAITV(7);  SBAR(); GLOAD(2, 2, 23)                MM(3, 17)
    WAITV(6);  SBAR(); GLOAD(3, 3, 24)                MM(4, 18)
    WAITV(5);  SBAR(); GLOAD(4, 4, 25)                MM(5, 19)
    WAITV(5);  SBAR();                                MM(6, 20)
    WAITV(4);  SBAR();                                MM(0, 21)
    WAITV(3);  SBAR();                                MM(1, 22)
    WAITV(2);  SBAR();                                MM(2, 23)
    WAITV(1);  SBAR();                                MM(3, 24)
    WAITV(0);  SBAR();                                MM(4, 25)

    // D layout: col = lane&15 = co, row = quad*4 + i. Coalesced writes.
#pragma unroll
    for (int i = 0; i < 4; ++i) {
        int p = base + quad * 4 + i;
        if (p < N) {
            out[(size_t)p * COUT + m]      = acc0[i];
            out[(size_t)p * COUT + m + 16] = acc1[i];
        }
    }
}

extern "C" void kernel_launch(void* const* d_in, const int* in_sizes, int n_in,
                              void* d_out, int out_size, void* d_ws, size_t ws_size,
                              hipStream_t stream) {
    const float* feats = (const float*)d_in[0];   // [N, 32]
    const int*   pos   = (const int*)d_in[1];     // [N, 3]
    const float* wt    = (const float*)d_in[2];   // [27, 32, 32]
    float* out = (float*)d_out;                   // [N, 32]
    int N = in_sizes[0] / CIN;

    char* ws = (char*)d_ws;
    size_t off = 0;
    int* table = (int*)(ws + off);            off += (size_t)GRID * GRID * GRID * 4; // 8 MB
    unsigned short* wtT = (unsigned short*)(ws + off); off += 65536;                 // 64 KB
    unsigned* featsB = (unsigned*)(ws + off);                             // 32 MB + 64 B

    hipMemsetAsync(table, 0xFF, (size_t)GRID * GRID * GRID * 4, stream);

    int elems4 = N * CIN / 4;
    prep_kernel<<<(elems4 + 255) / 256, 256, 0, stream>>>(
        feats, pos, wt, table, wtT, featsB, N, elems4);

    int numTiles = (N + 15) / 16;
    int nwg = (numTiles + 7) / 8;     // 8 waves (512 threads) per block
    conv_kernel<<<nwg, 512, 0, stream>>>((const unsigned short*)featsB, pos, wtT,
                                         table, out, N);
}